// Round 10
// baseline (13.508 us; speedup 1.0000x reference)
//
#include <hip/hip_runtime.h>
#include <math.h>

#define CDIV(a,b) (((a)+(b)-1)/(b))
#define NBLK 256     // k_rest grid: <= CU count -> co-resident -> grid barrier safe
#define TPB  1024
#define NWAVE (TPB / 64)
#define SCAN_BLOCKS 2048
#define SCAN_TPB 512
#define SCAN_NW (SCAN_TPB / 64)

// ctrl layout (int index), zeroed by k_scan block 0 each call (ctrl is consumed
// only by k_rest, which launches strictly after k_scan completes):
//   [0..15] barrier counters   [18] spTotal (float)

__device__ inline void gbar(int* __restrict__ cnts, int k) {
    __syncthreads();
    if (threadIdx.x == 0) {
        __threadfence();
        atomicAdd(&cnts[k], 1);
        while (atomicAdd(&cnts[k], 0) < NBLK) __builtin_amdgcn_s_sleep(2);
        __threadfence();
    }
    __syncthreads();
}

// ---------------------------------------------------------------------------
// k_scan: high-occupancy streaming pass. Soft-threshold all rows: write h0
// only for nonzero rows, rowNnz unconditionally (0/1), per-block nnz and
// reg-loss partials into slots (no atomics, no pre-zeroed state anywhere).
__global__ __launch_bounds__(SCAN_TPB) void k_scan(
    const float* __restrict__ weight, const float* __restrict__ s,
    const int* __restrict__ users, const int* __restrict__ pos,
    const int* __restrict__ neg,
    float* __restrict__ h0, int* __restrict__ rowNnz,
    int* __restrict__ ctrl, int* __restrict__ nnzSlots,
    float* __restrict__ regSlots, int N, int B)
{
    __shared__ int   shi[SCAN_NW];
    __shared__ float shf[SCAN_NW];
    const int tid  = threadIdx.x;
    const int lane = tid & 63, wid = tid >> 6;
    const int gsize = SCAN_BLOCKS * SCAN_TPB;
    const int gtid  = blockIdx.x * SCAN_TPB + tid;
    const float t  = 1.0f / (1.0f + expf(-s[0]));
    const float4* __restrict__ wf4  = (const float4*)weight;
    float4* __restrict__       h0f4 = (float4*)h0;

    if (blockIdx.x == 0 && tid < 64) ctrl[tid] = 0;   // ctrl used only by k_rest

    int   nzc = 0;
    float ss  = 0.0f;

    // A1: threshold scan over N*16 float4 elements (row = 16 consecutive f4)
    {
        const int total = N * 16;
        const int grp16 = (lane >> 4) << 4;
        auto proc = [&](int idx, float4 v) {
            float4 r;
            r.x = copysignf(fmaxf(fabsf(v.x) - t, 0.0f), v.x);
            r.y = copysignf(fmaxf(fabsf(v.y) - t, 0.0f), v.y);
            r.z = copysignf(fmaxf(fabsf(v.z) - t, 0.0f), v.z);
            r.w = copysignf(fmaxf(fabsf(v.w) - t, 0.0f), v.w);
            int nzl = (r.x != 0.0f) | (r.y != 0.0f) | (r.z != 0.0f) | (r.w != 0.0f);
            unsigned long long m = __ballot(nzl);
            int rowm = (int)((m >> grp16) & 0xFFFFull);   // row-uniform
            if (rowm) h0f4[idx] = r;                      // zero rows never read
            if ((idx & 15) == 0) { rowNnz[idx >> 4] = (rowm != 0); nzc += (rowm != 0); }
        };
        int idx = gtid;
        while (idx + gsize < total) {        // 2-deep independent loads
            float4 a0 = wf4[idx];
            float4 a1 = wf4[idx + gsize];
            proc(idx, a0); proc(idx + gsize, a1);
            idx += 2 * gsize;
        }
        if (idx < total) { float4 a0 = wf4[idx]; proc(idx, a0); }
    }

    // A2: reg-loss gather over sampled rows (L2/L3-resident after A1)
    {
        const int tot = 3 * B * 16;
        for (int g2 = gtid; g2 < tot; g2 += gsize) {
            int j = g2 >> 4, l16 = g2 & 15;
            int idx = (j < B) ? users[j] : ((j < 2 * B) ? pos[j - B] : neg[j - 2 * B]);
            float4 e = *(const float4*)(weight + (size_t)idx * 64 + l16 * 4);
            ss += e.x * e.x + e.y * e.y + e.z * e.z + e.w * e.w;
        }
    }

    for (int m = 1; m < 64; m <<= 1) {
        nzc += __shfl_xor(nzc, m);
        ss  += __shfl_xor(ss, m);
    }
    if (lane == 0) { shi[wid] = nzc; shf[wid] = ss; }
    __syncthreads();
    if (tid == 0) {
        int   a = 0; float f = 0.0f;
        for (int i = 0; i < SCAN_NW; ++i) { a += shi[i]; f += shf[i]; }
        nnzSlots[blockIdx.x] = a;
        regSlots[blockIdx.x] = f;
    }
}

// ---------------------------------------------------------------------------
// k_rest: one fused entry reduction (gate + reg_sum) -> either finalize
// (gated, block 0) or run the full CSR + 3xSpMM pipeline behind grid barriers.
__global__ __launch_bounds__(TPB) void k_rest(
    const float* __restrict__ weight, const float* __restrict__ s,
    const int* __restrict__ src, const int* __restrict__ dst,
    const int* __restrict__ users, const int* __restrict__ pos,
    const int* __restrict__ neg,
    int* __restrict__ ctrl, const int* __restrict__ nnzSlots,
    const float* __restrict__ regSlots,
    int* __restrict__ deg, int* __restrict__ chunkSums,
    int* __restrict__ rowptr, int* __restrict__ cursor, float* __restrict__ dinv,
    int2* __restrict__ edgep, const float* __restrict__ h0,
    float* __restrict__ h1, float* __restrict__ h2,
    const int* __restrict__ rowNnz,
    float* __restrict__ out, int N, int E, int B)
{
    __shared__ float sampT[48 * 64];
    __shared__ int   shi[NWAVE];
    __shared__ float shf[NWAVE];
    const int tid  = threadIdx.x;
    const int b    = blockIdx.x;
    const int lane = tid & 63, wid = tid >> 6;
    const int gsize = NBLK * TPB;
    const int gtid  = b * TPB + tid;
    const float t  = 1.0f / (1.0f + expf(-s[0]));
    float* spTotal = (float*)(ctrl + 18);

    // fused gate + reg_sum reduction (8 KB + 8 KB, L2-resident)
    int gate;
    float reg_sum;
    {
        int a = 0; float r = 0.0f;
        for (int i = tid; i < SCAN_BLOCKS; i += TPB) {
            a += nnzSlots[i];
            r += regSlots[i];
        }
        for (int m = 1; m < 64; m <<= 1) {
            a += __shfl_xor(a, m);
            r += __shfl_xor(r, m);
        }
        if (lane == 0) { shi[wid] = a; shf[wid] = r; }
        __syncthreads();
        int ti = 0; float tf = 0.0f;
        for (int w = 0; w < NWAVE; ++w) { ti += shi[w]; tf += shf[w]; }
        gate = ti; reg_sum = tf;
        __syncthreads();
    }

    if (gate == 0) {
        // sparse_v == 0 everywhere -> scores 0 -> loss_emb = ln 2 exactly.
        if (b == 0 && tid == 0) {
            float bm = (float)B;
            float loss_emb = 0.69314718056f;
            float reg_loss = 0.5f * reg_sum / bm * 1e-4f;
            float s0 = s[0];
            float s_loss = 0.5f * s0 * s0 / bm * 1e-4f;
            out[0] = loss_emb + reg_loss + s_loss;
            out[1] = loss_emb;
            out[2] = reg_loss;
            out[3] = s_loss;
        }
        return;
    }

    // ======================= nnz > 0 path ==================================
    const int sb = b * 16;
    const int l16 = tid & 15;

    // samp tile init in LDS (recompute threshold rows): 0..15=u,16..31=p,32..47=n
    for (int m2 = tid >> 4; m2 < 48; m2 += TPB / 16) {
        int kind = m2 >> 4, k = m2 & 15;
        int gj = sb + k;
        float4 rr = make_float4(0.f, 0.f, 0.f, 0.f);
        if (gj < B) {
            int idx = kind == 0 ? users[gj] : kind == 1 ? pos[gj] : neg[gj];
            float4 e = *(const float4*)(weight + (size_t)idx * 64 + l16 * 4);
            rr.x = copysignf(fmaxf(fabsf(e.x) - t, 0.0f), e.x);
            rr.y = copysignf(fmaxf(fabsf(e.y) - t, 0.0f), e.y);
            rr.z = copysignf(fmaxf(fabsf(e.z) - t, 0.0f), e.z);
            rr.w = copysignf(fmaxf(fabsf(e.w) - t, 0.0f), e.w);
        }
        *(float4*)(&sampT[m2 * 64 + l16 * 4]) = rr;
    }

    // P0: zero in-degree
    for (int i = gtid; i < N; i += gsize) deg[i] = 0;
    gbar(ctrl, 1);
    // P1: histogram
    for (int e = gtid; e < E; e += gsize) atomicAdd(&deg[dst[e]], 1);
    gbar(ctrl, 2);

    // P2a: per-chunk sums (chunk = 4096 = 1024 thr x 4)
    const int nchunk = (N + 4095) >> 12;
    for (int c = b; c < nchunk; c += NBLK) {
        int base = (c << 12) + tid * 4;
        int sum = 0;
        if (base + 3 < N) {
            int4 v = *(const int4*)(deg + base);
            sum = v.x + v.y + v.z + v.w;
        } else {
            for (int k = 0; k < 4; ++k) if (base + k < N) sum += deg[base + k];
        }
        for (int m = 1; m < 64; m <<= 1) sum += __shfl_xor(sum, m);
        __syncthreads();
        if (lane == 0) shi[wid] = sum;
        __syncthreads();
        if (tid == 0) {
            int tt = 0;
            for (int w = 0; w < NWAVE; ++w) tt += shi[w];
            chunkSums[c] = tt;
        }
        __syncthreads();
    }
    gbar(ctrl, 3);

    // P2b: block 0 exclusive-scans chunkSums; rowptr[N] = total
    if (b == 0) {
        int c0 = tid * 4;
        int a0 = (c0 + 0 < nchunk) ? chunkSums[c0 + 0] : 0;
        int a1 = (c0 + 1 < nchunk) ? chunkSums[c0 + 1] : 0;
        int a2 = (c0 + 2 < nchunk) ? chunkSums[c0 + 2] : 0;
        int a3 = (c0 + 3 < nchunk) ? chunkSums[c0 + 3] : 0;
        int tot = a0 + a1 + a2 + a3;
        int incl = tot;
        for (int off = 1; off < 64; off <<= 1) {
            int tt = __shfl_up(incl, off);
            if (lane >= off) incl += tt;
        }
        __syncthreads();
        if (lane == 63) shi[wid] = incl;
        __syncthreads();
        int wp = 0;
        for (int w = 0; w < wid; ++w) wp += shi[w];
        int excl = wp + incl - tot;
        if (c0 + 0 < nchunk) chunkSums[c0 + 0] = excl;
        if (c0 + 1 < nchunk) chunkSums[c0 + 1] = excl + a0;
        if (c0 + 2 < nchunk) chunkSums[c0 + 2] = excl + a0 + a1;
        if (c0 + 3 < nchunk) chunkSums[c0 + 3] = excl + a0 + a1 + a2;
        if (tid == 0) {
            int tt = 0;
            for (int w = 0; w < NWAVE; ++w) tt += shi[w];
            rowptr[N] = tt;
        }
    }
    gbar(ctrl, 4);

    // P2c: per-chunk local scan + chunk offset -> rowptr, cursor, dinv
    for (int c = b; c < nchunk; c += NBLK) {
        int base = (c << 12) + tid * 4;
        int v0 = 0, v1 = 0, v2 = 0, v3 = 0;
        if (base + 3 < N) {
            int4 v = *(const int4*)(deg + base);
            v0 = v.x; v1 = v.y; v2 = v.z; v3 = v.w;
        } else {
            if (base + 0 < N) v0 = deg[base + 0];
            if (base + 1 < N) v1 = deg[base + 1];
            if (base + 2 < N) v2 = deg[base + 2];
        }
        int tot = v0 + v1 + v2 + v3;
        int incl = tot;
        for (int off = 1; off < 64; off <<= 1) {
            int tt = __shfl_up(incl, off);
            if (lane >= off) incl += tt;
        }
        __syncthreads();
        if (lane == 63) shi[wid] = incl;
        __syncthreads();
        int wp = 0;
        for (int w = 0; w < wid; ++w) wp += shi[w];
        int excl = chunkSums[c] + wp + incl - tot;
        int e0 = excl, e1 = e0 + v0, e2 = e1 + v1, e3 = e2 + v2;
        if (base + 0 < N) { rowptr[base+0] = e0; cursor[base+0] = e0; dinv[base+0] = v0 > 0 ? rsqrtf((float)v0) : 0.f; }
        if (base + 1 < N) { rowptr[base+1] = e1; cursor[base+1] = e1; dinv[base+1] = v1 > 0 ? rsqrtf((float)v1) : 0.f; }
        if (base + 2 < N) { rowptr[base+2] = e2; cursor[base+2] = e2; dinv[base+2] = v2 > 0 ? rsqrtf((float)v2) : 0.f; }
        if (base + 3 < N) { rowptr[base+3] = e3; cursor[base+3] = e3; dinv[base+3] = v3 > 0 ? rsqrtf((float)v3) : 0.f; }
        __syncthreads();
    }
    gbar(ctrl, 5);

    // P3: scatter edges into CSR order; payload packed 8B = (src, adj)
    for (int e = gtid; e < E; e += gsize) {
        int d = dst[e], sN = src[e];
        int k = atomicAdd(&cursor[d], 1);
        edgep[k] = make_int2(sN, __float_as_int(dinv[sN] * dinv[d]));
    }
    gbar(ctrl, 6);

    auto spmm = [&](const float* hin, float* hout, const int* flags) {
        for (int g2 = gtid; g2 < N * 16; g2 += gsize) {
            int node = g2 >> 4, l = g2 & 15;
            int beg = rowptr[node], end = rowptr[node + 1];
            float4 acc = make_float4(0.f, 0.f, 0.f, 0.f);
            for (int k = beg; k < end; ++k) {
                int2 ep = edgep[k];
                if (flags && !flags[ep.x]) continue;
                float a = __int_as_float(ep.y);
                float4 v = *(const float4*)(hin + (size_t)ep.x * 64 + l * 4);
                acc.x = fmaf(a, v.x, acc.x);
                acc.y = fmaf(a, v.y, acc.y);
                acc.z = fmaf(a, v.z, acc.z);
                acc.w = fmaf(a, v.w, acc.w);
            }
            *(float4*)(hout + (size_t)node * 64 + l * 4) = acc;
        }
    };
    auto samp_add = [&](const float* h) {
        for (int m2 = tid >> 4; m2 < 48; m2 += TPB / 16) {
            int kind = m2 >> 4, k = m2 & 15;
            int gj = sb + k;
            if (gj < B) {
                int idx = kind == 0 ? users[gj] : kind == 1 ? pos[gj] : neg[gj];
                float4 v = *(const float4*)(h + (size_t)idx * 64 + l16 * 4);
                float* p = &sampT[m2 * 64 + l16 * 4];
                p[0] += v.x; p[1] += v.y; p[2] += v.z; p[3] += v.w;
            }
        }
    };

    // P4..P7: 3 SpMM layers with sampled-row accumulation
    spmm(h0, h1, rowNnz);
    gbar(ctrl, 7);
    samp_add(h1);
    spmm(h1, h2, nullptr);
    gbar(ctrl, 8);
    samp_add(h2);
    spmm(h2, h1, nullptr);
    gbar(ctrl, 9);
    samp_add(h1);
    __syncthreads();

    // Scores from LDS: 16 threads per sample (k = tid>>4 < 16)
    {
        int k = tid >> 4;
        float sp = 0.0f;
        int gj = sb + k;
        if (k < 16 && gj < B) {
            float4 u = *(const float4*)(&sampT[(0 * 16 + k) * 64 + l16 * 4]);
            float4 p = *(const float4*)(&sampT[(1 * 16 + k) * 64 + l16 * 4]);
            float4 q = *(const float4*)(&sampT[(2 * 16 + k) * 64 + l16 * 4]);
            float ps = u.x * p.x + u.y * p.y + u.z * p.z + u.w * p.w;
            float ns = u.x * q.x + u.y * q.y + u.z * q.z + u.w * q.w;
            for (int m = 1; m < 16; m <<= 1) {
                ps += __shfl_xor(ps, m);
                ns += __shfl_xor(ns, m);
            }
            if (l16 == 0) {
                float x = (ns - ps) * 0.0625f;  // all_emb = acc/4 -> scale 1/16
                sp = fmaxf(x, 0.0f) + log1pf(expf(-fabsf(x)));
            }
        }
        for (int m = 1; m < 64; m <<= 1) sp += __shfl_xor(sp, m);
        if (lane == 0) shf[wid] = sp;
        __syncthreads();
        if (tid == 0) {
            float tt = 0.0f;
            for (int w = 0; w < NWAVE; ++w) tt += shf[w];
            atomicAdd(spTotal, tt);
        }
    }
    gbar(ctrl, 10);

    if (b == 0 && tid == 0) {
        float bm = (float)B;
        float loss_emb = atomicAdd(spTotal, 0.0f) / bm;
        float reg_loss = 0.5f * reg_sum / bm * 1e-4f;
        float s0 = s[0];
        float s_loss = 0.5f * s0 * s0 / bm * 1e-4f;
        out[0] = loss_emb + reg_loss + s_loss;
        out[1] = loss_emb;
        out[2] = reg_loss;
        out[3] = s_loss;
    }
}

// ---------------------------------------------------------------------------
extern "C" void kernel_launch(void* const* d_in, const int* in_sizes, int n_in,
                              void* d_out, int out_size, void* d_ws, size_t ws_size,
                              hipStream_t stream) {
    const float* weight = (const float*)d_in[0];
    const float* s      = (const float*)d_in[1];
    const int*   src    = (const int*)d_in[2];
    const int*   dst    = (const int*)d_in[3];
    const int*   users  = (const int*)d_in[4];
    const int*   pos    = (const int*)d_in[5];
    const int*   neg    = (const int*)d_in[6];

    const int D = 64;
    const int N = in_sizes[0] / D;
    const int E = in_sizes[2];
    const int B = in_sizes[4];

    char* wp = (char*)d_ws;
    auto alloc = [&](size_t bytes) -> void* {
        void* p = (void*)wp;
        wp += (bytes + 255) & ~(size_t)255;
        return p;
    };
    int*   ctrl     = (int*)alloc(256);
    int*   nnzSlots = (int*)alloc((size_t)SCAN_BLOCKS * 4);
    float* regSlots = (float*)alloc((size_t)SCAN_BLOCKS * 4);
    int*   rowNnz   = (int*)alloc((size_t)N * 4);
    int*   deg      = (int*)alloc((size_t)N * 4);
    int*   chunkSums= (int*)alloc((size_t)4096 * 4);
    int*   rowptr   = (int*)alloc((size_t)(N + 1) * 4);
    int*   cursor   = (int*)alloc((size_t)N * 4);
    float* dinv     = (float*)alloc((size_t)N * 4);
    int2*  edgep    = (int2*)alloc((size_t)E * 8);
    float* h0       = (float*)alloc((size_t)N * D * 4);
    float* h1       = (float*)alloc((size_t)N * D * 4);
    float* h2       = (float*)alloc((size_t)N * D * 4);

    k_scan<<<SCAN_BLOCKS, SCAN_TPB, 0, stream>>>(weight, s, users, pos, neg,
                                                 h0, rowNnz, ctrl, nnzSlots,
                                                 regSlots, N, B);
    k_rest<<<NBLK, TPB, 0, stream>>>(weight, s, src, dst, users, pos, neg,
                                     ctrl, nnzSlots, regSlots, deg, chunkSums,
                                     rowptr, cursor, dinv, edgep, h0, h1, h2,
                                     rowNnz, (float*)d_out, N, E, B);
}

// Round 11
// 12.577 us; speedup vs baseline: 1.0740x; 1.0740x over previous
//
#include <hip/hip_runtime.h>
#include <math.h>

#define CDIV(a,b) (((a)+(b)-1)/(b))
#define NBLK 256     // k_rest grid: <= CU count -> co-resident -> grid barrier safe
#define TPB  1024
#define NWAVE (TPB / 64)
#define SCAN_BLOCKS 2048
#define SCAN_TPB 256

// ctrl layout (int index), zeroed by k_scan block 0 each call (ctrl is consumed
// only by k_rest, which launches strictly after k_scan completes):
//   [0..15] barrier counters   [18] spTotal (float)

__device__ inline void gbar(int* __restrict__ cnts, int k) {
    __syncthreads();
    if (threadIdx.x == 0) {
        __threadfence();
        atomicAdd(&cnts[k], 1);
        while (atomicAdd(&cnts[k], 0) < NBLK) __builtin_amdgcn_s_sleep(2);
        __threadfence();
    }
    __syncthreads();
}

// ---------------------------------------------------------------------------
// k_scan: high-occupancy streaming pass. Soft-threshold all rows: write h0
// only for nonzero rows, rowNnz unconditionally (0/1), per-block nnz and
// reg-loss partials into slots (no atomics, no pre-zeroed state anywhere).
// NOTE (r10 post-mortem): SCAN_TPB=256 + 4-deep unroll beats 512 + 2-deep
// (12.5 vs 13.5 µs) — per-thread MLP matters more than wave count here.
__global__ __launch_bounds__(SCAN_TPB) void k_scan(
    const float* __restrict__ weight, const float* __restrict__ s,
    const int* __restrict__ users, const int* __restrict__ pos,
    const int* __restrict__ neg,
    float* __restrict__ h0, int* __restrict__ rowNnz,
    int* __restrict__ ctrl, int* __restrict__ nnzSlots,
    float* __restrict__ regSlots, int N, int B)
{
    __shared__ int   shi[SCAN_TPB / 64];
    __shared__ float shf[SCAN_TPB / 64];
    const int tid  = threadIdx.x;
    const int lane = tid & 63, wid = tid >> 6;
    const int gsize = SCAN_BLOCKS * SCAN_TPB;
    const int gtid  = blockIdx.x * SCAN_TPB + tid;
    const float t  = 1.0f / (1.0f + expf(-s[0]));
    const float4* __restrict__ wf4  = (const float4*)weight;
    float4* __restrict__       h0f4 = (float4*)h0;

    if (blockIdx.x == 0 && tid < 64) ctrl[tid] = 0;   // ctrl used only by k_rest

    int   nzc = 0;
    float ss  = 0.0f;

    // A1: threshold scan over N*16 float4 elements (row = 16 consecutive f4)
    {
        const int total = N * 16;
        const int grp16 = (lane >> 4) << 4;
        auto proc = [&](int idx, float4 v) {
            float4 r;
            r.x = copysignf(fmaxf(fabsf(v.x) - t, 0.0f), v.x);
            r.y = copysignf(fmaxf(fabsf(v.y) - t, 0.0f), v.y);
            r.z = copysignf(fmaxf(fabsf(v.z) - t, 0.0f), v.z);
            r.w = copysignf(fmaxf(fabsf(v.w) - t, 0.0f), v.w);
            int nzl = (r.x != 0.0f) | (r.y != 0.0f) | (r.z != 0.0f) | (r.w != 0.0f);
            unsigned long long m = __ballot(nzl);
            int rowm = (int)((m >> grp16) & 0xFFFFull);   // row-uniform
            if (rowm) h0f4[idx] = r;                      // zero rows never read
            if ((idx & 15) == 0) { rowNnz[idx >> 4] = (rowm != 0); nzc += (rowm != 0); }
        };
        int idx = gtid;
        while (idx + 3 * gsize < total) {
            float4 a0 = wf4[idx];
            float4 a1 = wf4[idx + gsize];
            float4 a2 = wf4[idx + 2 * gsize];
            float4 a3 = wf4[idx + 3 * gsize];
            proc(idx, a0); proc(idx + gsize, a1);
            proc(idx + 2 * gsize, a2); proc(idx + 3 * gsize, a3);
            idx += 4 * gsize;
        }
        while (idx < total) { float4 a0 = wf4[idx]; proc(idx, a0); idx += gsize; }
    }

    // A2: reg-loss gather over sampled rows
    {
        const int tot = 3 * B * 16;
        for (int g2 = gtid; g2 < tot; g2 += gsize) {
            int j = g2 >> 4, l16 = g2 & 15;
            int idx = (j < B) ? users[j] : ((j < 2 * B) ? pos[j - B] : neg[j - 2 * B]);
            float4 e = *(const float4*)(weight + (size_t)idx * 64 + l16 * 4);
            ss += e.x * e.x + e.y * e.y + e.z * e.z + e.w * e.w;
        }
    }

    for (int m = 1; m < 64; m <<= 1) {
        nzc += __shfl_xor(nzc, m);
        ss  += __shfl_xor(ss, m);
    }
    if (lane == 0) { shi[wid] = nzc; shf[wid] = ss; }
    __syncthreads();
    if (tid == 0) {
        int   a = 0; float f = 0.0f;
        for (int i = 0; i < SCAN_TPB / 64; ++i) { a += shi[i]; f += shf[i]; }
        nnzSlots[blockIdx.x] = a;
        regSlots[blockIdx.x] = f;
    }
}

// ---------------------------------------------------------------------------
// k_rest: per-block gate from nnzSlots -> either finalize (gated, block 0) or
// run the full CSR + 3xSpMM pipeline behind hand-rolled grid barriers.
__global__ __launch_bounds__(TPB) void k_rest(
    const float* __restrict__ weight, const float* __restrict__ s,
    const int* __restrict__ src, const int* __restrict__ dst,
    const int* __restrict__ users, const int* __restrict__ pos,
    const int* __restrict__ neg,
    int* __restrict__ ctrl, const int* __restrict__ nnzSlots,
    const float* __restrict__ regSlots,
    int* __restrict__ deg, int* __restrict__ chunkSums,
    int* __restrict__ rowptr, int* __restrict__ cursor, float* __restrict__ dinv,
    int2* __restrict__ edgep, const float* __restrict__ h0,
    float* __restrict__ h1, float* __restrict__ h2,
    const int* __restrict__ rowNnz,
    float* __restrict__ out, int N, int E, int B)
{
    __shared__ float sampT[48 * 64];
    __shared__ int   shi[NWAVE];
    __shared__ float shf[NWAVE];
    const int tid  = threadIdx.x;
    const int b    = blockIdx.x;
    const int lane = tid & 63, wid = tid >> 6;
    const int gsize = NBLK * TPB;
    const int gtid  = b * TPB + tid;
    const float t  = 1.0f / (1.0f + expf(-s[0]));
    float* spTotal = (float*)(ctrl + 18);

    // gate = sum(nnzSlots) — every block computes it (8 KB, L2-resident)
    int gate;
    {
        int a = 0;
        for (int i = tid; i < SCAN_BLOCKS; i += TPB) a += nnzSlots[i];
        for (int m = 1; m < 64; m <<= 1) a += __shfl_xor(a, m);
        if (lane == 0) shi[wid] = a;
        __syncthreads();
        int tt = 0;
        for (int w = 0; w < NWAVE; ++w) tt += shi[w];
        gate = tt;
        __syncthreads();
    }

    // helper: block-local sum of regSlots[SCAN_BLOCKS]
    auto reg_sum_blk = [&]() -> float {
        float r = 0.0f;
        for (int i = tid; i < SCAN_BLOCKS; i += TPB) r += regSlots[i];
        for (int m = 1; m < 64; m <<= 1) r += __shfl_xor(r, m);
        if (lane == 0) shf[wid] = r;
        __syncthreads();
        float tt = 0.0f;
        for (int w = 0; w < NWAVE; ++w) tt += shf[w];
        return tt;
    };

    if (gate == 0) {
        // sparse_v == 0 everywhere -> scores 0 -> loss_emb = ln 2 exactly.
        if (b == 0) {
            float reg_sum = reg_sum_blk();
            if (tid == 0) {
                float bm = (float)B;
                float loss_emb = 0.69314718056f;
                float reg_loss = 0.5f * reg_sum / bm * 1e-4f;
                float s0 = s[0];
                float s_loss = 0.5f * s0 * s0 / bm * 1e-4f;
                out[0] = loss_emb + reg_loss + s_loss;
                out[1] = loss_emb;
                out[2] = reg_loss;
                out[3] = s_loss;
            }
        }
        return;
    }

    // ======================= nnz > 0 path ==================================
    const int sb = b * 16;
    const int l16 = tid & 15;

    // samp tile init in LDS (recompute threshold rows): 0..15=u,16..31=p,32..47=n
    for (int m2 = tid >> 4; m2 < 48; m2 += TPB / 16) {
        int kind = m2 >> 4, k = m2 & 15;
        int gj = sb + k;
        float4 rr = make_float4(0.f, 0.f, 0.f, 0.f);
        if (gj < B) {
            int idx = kind == 0 ? users[gj] : kind == 1 ? pos[gj] : neg[gj];
            float4 e = *(const float4*)(weight + (size_t)idx * 64 + l16 * 4);
            rr.x = copysignf(fmaxf(fabsf(e.x) - t, 0.0f), e.x);
            rr.y = copysignf(fmaxf(fabsf(e.y) - t, 0.0f), e.y);
            rr.z = copysignf(fmaxf(fabsf(e.z) - t, 0.0f), e.z);
            rr.w = copysignf(fmaxf(fabsf(e.w) - t, 0.0f), e.w);
        }
        *(float4*)(&sampT[m2 * 64 + l16 * 4]) = rr;
    }

    // P0: zero in-degree
    for (int i = gtid; i < N; i += gsize) deg[i] = 0;
    gbar(ctrl, 1);
    // P1: histogram
    for (int e = gtid; e < E; e += gsize) atomicAdd(&deg[dst[e]], 1);
    gbar(ctrl, 2);

    // P2a: per-chunk sums (chunk = 4096 = 1024 thr x 4)
    const int nchunk = (N + 4095) >> 12;
    for (int c = b; c < nchunk; c += NBLK) {
        int base = (c << 12) + tid * 4;
        int sum = 0;
        if (base + 3 < N) {
            int4 v = *(const int4*)(deg + base);
            sum = v.x + v.y + v.z + v.w;
        } else {
            for (int k = 0; k < 4; ++k) if (base + k < N) sum += deg[base + k];
        }
        for (int m = 1; m < 64; m <<= 1) sum += __shfl_xor(sum, m);
        __syncthreads();
        if (lane == 0) shi[wid] = sum;
        __syncthreads();
        if (tid == 0) {
            int tt = 0;
            for (int w = 0; w < NWAVE; ++w) tt += shi[w];
            chunkSums[c] = tt;
        }
        __syncthreads();
    }
    gbar(ctrl, 3);

    // P2b: block 0 exclusive-scans chunkSums; rowptr[N] = total
    if (b == 0) {
        int c0 = tid * 4;
        int a0 = (c0 + 0 < nchunk) ? chunkSums[c0 + 0] : 0;
        int a1 = (c0 + 1 < nchunk) ? chunkSums[c0 + 1] : 0;
        int a2 = (c0 + 2 < nchunk) ? chunkSums[c0 + 2] : 0;
        int a3 = (c0 + 3 < nchunk) ? chunkSums[c0 + 3] : 0;
        int tot = a0 + a1 + a2 + a3;
        int incl = tot;
        for (int off = 1; off < 64; off <<= 1) {
            int tt = __shfl_up(incl, off);
            if (lane >= off) incl += tt;
        }
        __syncthreads();
        if (lane == 63) shi[wid] = incl;
        __syncthreads();
        int wp = 0;
        for (int w = 0; w < wid; ++w) wp += shi[w];
        int excl = wp + incl - tot;
        if (c0 + 0 < nchunk) chunkSums[c0 + 0] = excl;
        if (c0 + 1 < nchunk) chunkSums[c0 + 1] = excl + a0;
        if (c0 + 2 < nchunk) chunkSums[c0 + 2] = excl + a0 + a1;
        if (c0 + 3 < nchunk) chunkSums[c0 + 3] = excl + a0 + a1 + a2;
        if (tid == 0) {
            int tt = 0;
            for (int w = 0; w < NWAVE; ++w) tt += shi[w];
            rowptr[N] = tt;
        }
    }
    gbar(ctrl, 4);

    // P2c: per-chunk local scan + chunk offset -> rowptr, cursor, dinv
    for (int c = b; c < nchunk; c += NBLK) {
        int base = (c << 12) + tid * 4;
        int v0 = 0, v1 = 0, v2 = 0, v3 = 0;
        if (base + 3 < N) {
            int4 v = *(const int4*)(deg + base);
            v0 = v.x; v1 = v.y; v2 = v.z; v3 = v.w;
        } else {
            if (base + 0 < N) v0 = deg[base + 0];
            if (base + 1 < N) v1 = deg[base + 1];
            if (base + 2 < N) v2 = deg[base + 2];
        }
        int tot = v0 + v1 + v2 + v3;
        int incl = tot;
        for (int off = 1; off < 64; off <<= 1) {
            int tt = __shfl_up(incl, off);
            if (lane >= off) incl += tt;
        }
        __syncthreads();
        if (lane == 63) shi[wid] = incl;
        __syncthreads();
        int wp = 0;
        for (int w = 0; w < wid; ++w) wp += shi[w];
        int excl = chunkSums[c] + wp + incl - tot;
        int e0 = excl, e1 = e0 + v0, e2 = e1 + v1, e3 = e2 + v2;
        if (base + 0 < N) { rowptr[base+0] = e0; cursor[base+0] = e0; dinv[base+0] = v0 > 0 ? rsqrtf((float)v0) : 0.f; }
        if (base + 1 < N) { rowptr[base+1] = e1; cursor[base+1] = e1; dinv[base+1] = v1 > 0 ? rsqrtf((float)v1) : 0.f; }
        if (base + 2 < N) { rowptr[base+2] = e2; cursor[base+2] = e2; dinv[base+2] = v2 > 0 ? rsqrtf((float)v2) : 0.f; }
        if (base + 3 < N) { rowptr[base+3] = e3; cursor[base+3] = e3; dinv[base+3] = v3 > 0 ? rsqrtf((float)v3) : 0.f; }
        __syncthreads();
    }
    gbar(ctrl, 5);

    // P3: scatter edges into CSR order; payload packed 8B = (src, adj)
    for (int e = gtid; e < E; e += gsize) {
        int d = dst[e], sN = src[e];
        int k = atomicAdd(&cursor[d], 1);
        edgep[k] = make_int2(sN, __float_as_int(dinv[sN] * dinv[d]));
    }
    gbar(ctrl, 6);

    auto spmm = [&](const float* hin, float* hout, const int* flags) {
        for (int g2 = gtid; g2 < N * 16; g2 += gsize) {
            int node = g2 >> 4, l = g2 & 15;
            int beg = rowptr[node], end = rowptr[node + 1];
            float4 acc = make_float4(0.f, 0.f, 0.f, 0.f);
            for (int k = beg; k < end; ++k) {
                int2 ep = edgep[k];
                if (flags && !flags[ep.x]) continue;
                float a = __int_as_float(ep.y);
                float4 v = *(const float4*)(hin + (size_t)ep.x * 64 + l * 4);
                acc.x = fmaf(a, v.x, acc.x);
                acc.y = fmaf(a, v.y, acc.y);
                acc.z = fmaf(a, v.z, acc.z);
                acc.w = fmaf(a, v.w, acc.w);
            }
            *(float4*)(hout + (size_t)node * 64 + l * 4) = acc;
        }
    };
    auto samp_add = [&](const float* h) {
        for (int m2 = tid >> 4; m2 < 48; m2 += TPB / 16) {
            int kind = m2 >> 4, k = m2 & 15;
            int gj = sb + k;
            if (gj < B) {
                int idx = kind == 0 ? users[gj] : kind == 1 ? pos[gj] : neg[gj];
                float4 v = *(const float4*)(h + (size_t)idx * 64 + l16 * 4);
                float* p = &sampT[m2 * 64 + l16 * 4];
                p[0] += v.x; p[1] += v.y; p[2] += v.z; p[3] += v.w;
            }
        }
    };

    // P4..P7: 3 SpMM layers with sampled-row accumulation
    spmm(h0, h1, rowNnz);
    gbar(ctrl, 7);
    samp_add(h1);
    spmm(h1, h2, nullptr);
    gbar(ctrl, 8);
    samp_add(h2);
    spmm(h2, h1, nullptr);
    gbar(ctrl, 9);
    samp_add(h1);
    __syncthreads();

    // Scores from LDS: 16 threads per sample (k = tid>>4 < 16)
    {
        int k = tid >> 4;
        float sp = 0.0f;
        int gj = sb + k;
        if (k < 16 && gj < B) {
            float4 u = *(const float4*)(&sampT[(0 * 16 + k) * 64 + l16 * 4]);
            float4 p = *(const float4*)(&sampT[(1 * 16 + k) * 64 + l16 * 4]);
            float4 q = *(const float4*)(&sampT[(2 * 16 + k) * 64 + l16 * 4]);
            float ps = u.x * p.x + u.y * p.y + u.z * p.z + u.w * p.w;
            float ns = u.x * q.x + u.y * q.y + u.z * q.z + u.w * q.w;
            for (int m = 1; m < 16; m <<= 1) {
                ps += __shfl_xor(ps, m);
                ns += __shfl_xor(ns, m);
            }
            if (l16 == 0) {
                float x = (ns - ps) * 0.0625f;  // all_emb = acc/4 -> scale 1/16
                sp = fmaxf(x, 0.0f) + log1pf(expf(-fabsf(x)));
            }
        }
        for (int m = 1; m < 64; m <<= 1) sp += __shfl_xor(sp, m);
        if (lane == 0) shf[wid] = sp;
        __syncthreads();
        if (tid == 0) {
            float tt = 0.0f;
            for (int w = 0; w < NWAVE; ++w) tt += shf[w];
            atomicAdd(spTotal, tt);
        }
    }
    gbar(ctrl, 10);

    if (b == 0) {
        __syncthreads();
        float reg_sum = reg_sum_blk();
        if (tid == 0) {
            float bm = (float)B;
            float loss_emb = atomicAdd(spTotal, 0.0f) / bm;
            float reg_loss = 0.5f * reg_sum / bm * 1e-4f;
            float s0 = s[0];
            float s_loss = 0.5f * s0 * s0 / bm * 1e-4f;
            out[0] = loss_emb + reg_loss + s_loss;
            out[1] = loss_emb;
            out[2] = reg_loss;
            out[3] = s_loss;
        }
    }
}

// ---------------------------------------------------------------------------
extern "C" void kernel_launch(void* const* d_in, const int* in_sizes, int n_in,
                              void* d_out, int out_size, void* d_ws, size_t ws_size,
                              hipStream_t stream) {
    const float* weight = (const float*)d_in[0];
    const float* s      = (const float*)d_in[1];
    const int*   src    = (const int*)d_in[2];
    const int*   dst    = (const int*)d_in[3];
    const int*   users  = (const int*)d_in[4];
    const int*   pos    = (const int*)d_in[5];
    const int*   neg    = (const int*)d_in[6];

    const int D = 64;
    const int N = in_sizes[0] / D;
    const int E = in_sizes[2];
    const int B = in_sizes[4];

    char* wp = (char*)d_ws;
    auto alloc = [&](size_t bytes) -> void* {
        void* p = (void*)wp;
        wp += (bytes + 255) & ~(size_t)255;
        return p;
    };
    int*   ctrl     = (int*)alloc(256);
    int*   nnzSlots = (int*)alloc((size_t)SCAN_BLOCKS * 4);
    float* regSlots = (float*)alloc((size_t)SCAN_BLOCKS * 4);
    int*   rowNnz   = (int*)alloc((size_t)N * 4);
    int*   deg      = (int*)alloc((size_t)N * 4);
    int*   chunkSums= (int*)alloc((size_t)4096 * 4);
    int*   rowptr   = (int*)alloc((size_t)(N + 1) * 4);
    int*   cursor   = (int*)alloc((size_t)N * 4);
    float* dinv     = (float*)alloc((size_t)N * 4);
    int2*  edgep    = (int2*)alloc((size_t)E * 8);
    float* h0       = (float*)alloc((size_t)N * D * 4);
    float* h1       = (float*)alloc((size_t)N * D * 4);
    float* h2       = (float*)alloc((size_t)N * D * 4);

    k_scan<<<SCAN_BLOCKS, SCAN_TPB, 0, stream>>>(weight, s, users, pos, neg,
                                                 h0, rowNnz, ctrl, nnzSlots,
                                                 regSlots, N, B);
    k_rest<<<NBLK, TPB, 0, stream>>>(weight, s, src, dst, users, pos, neg,
                                     ctrl, nnzSlots, regSlots, deg, chunkSums,
                                     rowptr, cursor, dinv, edgep, h0, h1, h2,
                                     rowNnz, (float*)d_out, N, E, B);
}